// Round 6
// baseline (2054.709 us; speedup 1.0000x reference)
//
#include <hip/hip_runtime.h>
#include <hip/hip_bf16.h>
#include <cstddef>
#include <cstdint>

#define NN 2048      // nodes (M and K of the big GEMMs)
#define CIN 2
#define HH 32        // hidden
#define EMB 16
#define HOR 12
#define BB 32        // batch
#define TT 16        // time steps
#define GC 128       // 4*HH gate channels
#define XCOLS 1024   // B*T*C
#define HCOLS 1024   // B*H  (GEMM N dim)
#define KSPLIT 2
#define KS (NN / KSPLIT)          // 1024 per k-slice
#define NIT (KS / 32)             // 32 K-iterations
#define CSZ ((size_t)NN * HCOLS)  // one partial C: 2M floats
// Fused hi/lo layouts: A2[row][s][k] (row stride 4096 u16), B2[col][s][k]

typedef __attribute__((ext_vector_type(8))) short bf16x8;
typedef __attribute__((ext_vector_type(4))) float f32x4;
typedef unsigned short u16;

__device__ inline u16 f2bf(float f) {
    __hip_bfloat16 h = __float2bfloat16(f);
    return *reinterpret_cast<u16*>(&h);
}
__device__ inline float bf2f(u16 u) {
    __hip_bfloat16 h = *reinterpret_cast<__hip_bfloat16*>(&u);
    return __bfloat162float(h);
}
__device__ inline void split_bf(float v, u16& hi, u16& lo) {
    hi = f2bf(v);
    lo = f2bf(v - bf2f(hi));
}

// ---------------------------------------------------------------------------
// Kernel 1: A = softmax(relu(E1 @ E2^T)) -> A2[row][s][k] fused hi/lo layout.
// ---------------------------------------------------------------------------
__global__ __launch_bounds__(256) void adj_softmax(const float* __restrict__ E1,
                                                   const float* __restrict__ E2,
                                                   u16* __restrict__ A2) {
    const int i = blockIdx.x;
    __shared__ float red[256];
    float e1[EMB];
#pragma unroll
    for (int k = 0; k < EMB; ++k) e1[k] = E1[i * EMB + k];

    float s[8];
    float mx = -1e30f;
#pragma unroll
    for (int q = 0; q < 8; ++q) {
        const int j = q * 256 + threadIdx.x;
        float d = 0.f;
#pragma unroll
        for (int k = 0; k < EMB; ++k) d += e1[k] * E2[j * EMB + k];
        d = fmaxf(d, 0.0f);
        s[q] = d;
        mx = fmaxf(mx, d);
    }
    red[threadIdx.x] = mx;
    __syncthreads();
    for (int off = 128; off > 0; off >>= 1) {
        if (threadIdx.x < off) red[threadIdx.x] = fmaxf(red[threadIdx.x], red[threadIdx.x + off]);
        __syncthreads();
    }
    mx = red[0];
    __syncthreads();

    float sum = 0.f;
#pragma unroll
    for (int q = 0; q < 8; ++q) { s[q] = expf(s[q] - mx); sum += s[q]; }
    red[threadIdx.x] = sum;
    __syncthreads();
    for (int off = 128; off > 0; off >>= 1) {
        if (threadIdx.x < off) red[threadIdx.x] += red[threadIdx.x + off];
        __syncthreads();
    }
    const float inv = 1.0f / red[0];
#pragma unroll
    for (int q = 0; q < 8; ++q) {
        const float v = s[q] * inv;
        u16 hi, lo; split_bf(v, hi, lo);
        const size_t base = (size_t)i * 4096 + q * 256 + threadIdx.x;
        A2[base] = hi; A2[base + 2048] = lo;
    }
}

// ---------------------------------------------------------------------------
// Kernel 2: B2[col][s][node], col = (b*T+t)*C + c
// ---------------------------------------------------------------------------
__global__ __launch_bounds__(256) void transpose_x(const float* __restrict__ x,
                                                   u16* __restrict__ B2) {
    const int idx = blockIdx.x * 256 + threadIdx.x;
    const int col = idx >> 11;
    const int j   = idx & (NN - 1);
    const int bt  = col >> 1;
    const int c   = col & 1;
    const float v = x[((size_t)bt * NN + j) * CIN + c];
    u16 hi, lo; split_bf(v, hi, lo);
    const size_t base = (size_t)col * 4096 + j;
    B2[base] = hi; B2[base + 2048] = lo;
}

// ---------------------------------------------------------------------------
// Kernel 3: split-K bf16x3 MFMA GEMM, direct global->fragment loads, NO LDS,
// NO barriers. Cp[z][2048][1024] = A[.][z-slice] * B[z-slice][.]
// 128x64 block tile, 4 waves each 64x32 (4x2 of 16x16x32).
// A-frag: lane reads A2[m][s][q*8..+7] - 16B contiguous. Same for B (B^T).
// Fragments double-buffered in macro-named scalars (no arrays -> no scratch).
// ---------------------------------------------------------------------------
__global__ __launch_bounds__(256, 2) void gemm3d(const u16* __restrict__ A2,
                                                 const u16* __restrict__ B2,
                                                 float* __restrict__ Cp) {
    const int tid  = threadIdx.x;
    const int w    = tid >> 6;
    const int lane = tid & 63;
    const int m0 = blockIdx.y * 128;
    const int n0 = blockIdx.x * 64;
    const int k0 = blockIdx.z * KS;
    const int q  = lane >> 4;
    const int mr = lane & 15;
    const int wr = (w >> 1) * 64;
    const int wc = (w & 1) * 32;

    const u16* pa0 = A2 + (size_t)(m0 + wr +  0 + mr) * 4096 + k0 + q * 8;
    const u16* pa1 = A2 + (size_t)(m0 + wr + 16 + mr) * 4096 + k0 + q * 8;
    const u16* pa2 = A2 + (size_t)(m0 + wr + 32 + mr) * 4096 + k0 + q * 8;
    const u16* pa3 = A2 + (size_t)(m0 + wr + 48 + mr) * 4096 + k0 + q * 8;
    const u16* pb0 = B2 + (size_t)(n0 + wc +  0 + mr) * 4096 + k0 + q * 8;
    const u16* pb1 = B2 + (size_t)(n0 + wc + 16 + mr) * 4096 + k0 + q * 8;

    f32x4 acc00 = (f32x4)(0.f), acc01 = (f32x4)(0.f);
    f32x4 acc10 = (f32x4)(0.f), acc11 = (f32x4)(0.f);
    f32x4 acc20 = (f32x4)(0.f), acc21 = (f32x4)(0.f);
    f32x4 acc30 = (f32x4)(0.f), acc31 = (f32x4)(0.f);

    bf16x8 Xa0h, Xa0l, Xa1h, Xa1l, Xa2h, Xa2l, Xa3h, Xa3l, Xb0h, Xb0l, Xb1h, Xb1l;
    bf16x8 Ya0h, Ya0l, Ya1h, Ya1l, Ya2h, Ya2l, Ya3h, Ya3l, Yb0h, Yb0l, Yb1h, Yb1l;

#define LOADF(P)                                                                \
    P##a0h = *(const bf16x8*)pa0; P##a0l = *(const bf16x8*)(pa0 + 2048); pa0 += 32; \
    P##a1h = *(const bf16x8*)pa1; P##a1l = *(const bf16x8*)(pa1 + 2048); pa1 += 32; \
    P##a2h = *(const bf16x8*)pa2; P##a2l = *(const bf16x8*)(pa2 + 2048); pa2 += 32; \
    P##a3h = *(const bf16x8*)pa3; P##a3l = *(const bf16x8*)(pa3 + 2048); pa3 += 32; \
    P##b0h = *(const bf16x8*)pb0; P##b0l = *(const bf16x8*)(pb0 + 2048); pb0 += 32; \
    P##b1h = *(const bf16x8*)pb1; P##b1l = *(const bf16x8*)(pb1 + 2048); pb1 += 32;

#define MM(D, AH, AL, BH, BL)                                                   \
    D = __builtin_amdgcn_mfma_f32_16x16x32_bf16(AH, BH, D, 0, 0, 0);            \
    D = __builtin_amdgcn_mfma_f32_16x16x32_bf16(AH, BL, D, 0, 0, 0);            \
    D = __builtin_amdgcn_mfma_f32_16x16x32_bf16(AL, BH, D, 0, 0, 0);

#define MFMAF(P)                                                                \
    MM(acc00, P##a0h, P##a0l, P##b0h, P##b0l)                                   \
    MM(acc10, P##a1h, P##a1l, P##b0h, P##b0l)                                   \
    MM(acc20, P##a2h, P##a2l, P##b0h, P##b0l)                                   \
    MM(acc30, P##a3h, P##a3l, P##b0h, P##b0l)                                   \
    MM(acc01, P##a0h, P##a0l, P##b1h, P##b1l)                                   \
    MM(acc11, P##a1h, P##a1l, P##b1h, P##b1l)                                   \
    MM(acc21, P##a2h, P##a2l, P##b1h, P##b1l)                                   \
    MM(acc31, P##a3h, P##a3l, P##b1h, P##b1l)

    LOADF(X)
#pragma unroll 1
    for (int it = 0; it < NIT; it += 2) {
        LOADF(Y)
        MFMAF(X)
        LOADF(X)   // final body over-reads 64B into the next ws region - harmless, never consumed
        MFMAF(Y)
    }
#undef LOADF
#undef MM
#undef MFMAF

    float* Cs = Cp + (size_t)blockIdx.z * CSZ;
    const int colb = n0 + wc + mr;
    const int rowb = m0 + wr + q * 4;
#define ST(ACC, IT, JT)                                                         \
    Cs[(size_t)(rowb + IT * 16 + 0) * HCOLS + colb + JT * 16] = ACC[0];         \
    Cs[(size_t)(rowb + IT * 16 + 1) * HCOLS + colb + JT * 16] = ACC[1];         \
    Cs[(size_t)(rowb + IT * 16 + 2) * HCOLS + colb + JT * 16] = ACC[2];         \
    Cs[(size_t)(rowb + IT * 16 + 3) * HCOLS + colb + JT * 16] = ACC[3];
    ST(acc00, 0, 0) ST(acc10, 1, 0) ST(acc20, 2, 0) ST(acc30, 3, 0)
    ST(acc01, 0, 1) ST(acc11, 1, 1) ST(acc21, 2, 1) ST(acc31, 3, 1)
#undef ST
}

// ---------------------------------------------------------------------------
// Kernel 3b: AX = sum of KSPLIT k-slice partials (one-time, for the x path)
// ---------------------------------------------------------------------------
__global__ __launch_bounds__(256) void reduce_ax(const float* __restrict__ P,
                                                 float* __restrict__ AX) {
    const size_t idx = (size_t)blockIdx.x * 256 + threadIdx.x;
    const float4* P4 = (const float4*)P;
    const size_t q = CSZ / 4;
    float4 a = P4[idx], b = P4[idx + q];
    float4 r;
    r.x = a.x + b.x;
    r.y = a.y + b.y;
    r.z = a.z + b.z;
    r.w = a.w + b.w;
    ((float4*)AX)[idx] = r;
}

// ---------------------------------------------------------------------------
// Kernel 3c: weight prep. Whr[k][h][g] = Wh[k][g*32+h]; Wxr[c][h][g]; bfold.
// ---------------------------------------------------------------------------
__global__ __launch_bounds__(256) void prep_weights(const float* __restrict__ Wx,
                                                    const float* __restrict__ bx,
                                                    const float* __restrict__ Wh,
                                                    const float* __restrict__ bh,
                                                    float* __restrict__ Whr,
                                                    float* __restrict__ Wxr,
                                                    float* __restrict__ bfold) {
    const int tid = threadIdx.x;
#pragma unroll
    for (int r = 0; r < 16; ++r) {
        const int idx = tid * 16 + r;           // 4096
        const int k = idx >> 7, rem = idx & 127;
        const int h = rem >> 2, g = rem & 3;
        Whr[idx] = Wh[k * GC + g * HH + h];
    }
    {
        const int idx = tid;                    // 256
        const int c = idx >> 7, rem = idx & 127;
        const int h = rem >> 2, g = rem & 3;
        Wxr[idx] = Wx[c * GC + g * HH + h];
    }
    if (tid < 128) {
        const int h = tid >> 2, g = tid & 3;
        bfold[tid] = bx[g * HH + h] + bh[g * HH + h];
    }
}

// ---------------------------------------------------------------------------
// Kernel 4: gates + cell update, 64 nodes x 4 batches per block (weight
// staging amortized 4x). Writes h32 and hT2 (fused [col][s][node] layout).
// ---------------------------------------------------------------------------
__global__ __launch_bounds__(256) void gate_update(const float* __restrict__ AX,
                                                   const float* __restrict__ Ahp,
                                                   const float* __restrict__ Whr,
                                                   const float* __restrict__ Wxr,
                                                   const float* __restrict__ bfold,
                                                   float* __restrict__ c,
                                                   float* __restrict__ h32,
                                                   u16* __restrict__ hT2,
                                                   int t, int first) {
    const int n0 = blockIdx.x * 64;
    const int b0 = blockIdx.y * 4;
    const int tid = threadIdx.x;
    __shared__ float whr[4096];
    __shared__ float wxr[256];
    __shared__ float bfl[128];
    __shared__ float ah_s[64][33];
    __shared__ float axs[2][64];

#pragma unroll
    for (int r = 0; r < 4; ++r)
        *(float4*)&whr[(tid * 4 + r * 1024)] = *(const float4*)&Whr[(tid * 4 + r * 1024)];
    if (tid < 64)  *(float4*)&wxr[tid * 4] = *(const float4*)&Wxr[tid * 4];
    if (tid < 32)  *(float4*)&bfl[tid * 4] = *(const float4*)&bfold[tid * 4];

    const int nl = tid & 63;
    const int hq = tid >> 6;

#pragma unroll 1
    for (int bi = 0; bi < 4; ++bi) {
        const int b = b0 + bi;
        if (bi) __syncthreads();   // previous batch's readers done before restaging

        if (!first) {
            const int nls = tid >> 2;
            const int kq = (tid & 3) * 8;
            float4 a0 = make_float4(0, 0, 0, 0), a1 = make_float4(0, 0, 0, 0);
#pragma unroll
            for (int s = 0; s < KSPLIT; ++s) {
                const float* src = Ahp + s * CSZ + (size_t)(n0 + nls) * HCOLS + b * HH + kq;
                const float4 v0 = *(const float4*)src;
                const float4 v1 = *(const float4*)(src + 4);
                a0.x += v0.x; a0.y += v0.y; a0.z += v0.z; a0.w += v0.w;
                a1.x += v1.x; a1.y += v1.y; a1.z += v1.z; a1.w += v1.w;
            }
            ah_s[nls][kq + 0] = a0.x; ah_s[nls][kq + 1] = a0.y;
            ah_s[nls][kq + 2] = a0.z; ah_s[nls][kq + 3] = a0.w;
            ah_s[nls][kq + 4] = a1.x; ah_s[nls][kq + 5] = a1.y;
            ah_s[nls][kq + 6] = a1.z; ah_s[nls][kq + 7] = a1.w;
        }
        if (tid < 128) {
            const int which = tid >> 6, nls = tid & 63;
            axs[which][nls] = AX[(size_t)(n0 + nls) * XCOLS + (b * TT + t) * CIN + which];
        }
        __syncthreads();

        const float ax0 = axs[0][nl], ax1 = axs[1][nl];
        float acc[8][4];
#pragma unroll
        for (int u = 0; u < 8; ++u) {
            const int h = hq * 8 + u;
#pragma unroll
            for (int g = 0; g < 4; ++g)
                acc[u][g] = bfl[h * 4 + g] + ax0 * wxr[h * 4 + g] + ax1 * wxr[128 + h * 4 + g];
        }
        if (!first) {
            float ah_r[HH];
#pragma unroll
            for (int k = 0; k < HH; ++k) ah_r[k] = ah_s[nl][k];
#pragma unroll 4
            for (int k = 0; k < HH; ++k) {
                const float a = ah_r[k];
#pragma unroll
                for (int u = 0; u < 8; ++u) {
                    const float* wp = &whr[(k * HH + hq * 8 + u) * 4];
                    acc[u][0] += a * wp[0];
                    acc[u][1] += a * wp[1];
                    acc[u][2] += a * wp[2];
                    acc[u][3] += a * wp[3];
                }
            }
        }

        float cn[8], hn[8];
        const size_t off = (size_t)(n0 + nl) * HCOLS + b * HH + hq * 8;
        float4 c0o = make_float4(0, 0, 0, 0), c1o = make_float4(0, 0, 0, 0);
        if (!first) { c0o = *(const float4*)(c + off); c1o = *(const float4*)(c + off + 4); }
        const float cold[8] = {c0o.x, c0o.y, c0o.z, c0o.w, c1o.x, c1o.y, c1o.z, c1o.w};
#pragma unroll
        for (int u = 0; u < 8; ++u) {
            const float i_ = 1.0f / (1.0f + expf(-acc[u][0]));
            const float f_ = 1.0f / (1.0f + expf(-acc[u][1]));
            const float o_ = 1.0f / (1.0f + expf(-acc[u][2]));
            const float g_ = tanhf(acc[u][3]);
            const float c_t = f_ * cold[u] + i_ * g_;
            cn[u] = c_t;
            hn[u] = o_ * tanhf(c_t);
        }
        *(float4*)(c + off)       = make_float4(cn[0], cn[1], cn[2], cn[3]);
        *(float4*)(c + off + 4)   = make_float4(cn[4], cn[5], cn[6], cn[7]);
        *(float4*)(h32 + off)     = make_float4(hn[0], hn[1], hn[2], hn[3]);
        *(float4*)(h32 + off + 4) = make_float4(hn[4], hn[5], hn[6], hn[7]);
#pragma unroll
        for (int u = 0; u < 8; ++u) {
            u16 hh, hl; split_bf(hn[u], hh, hl);
            const size_t toff = (size_t)(b * HH + hq * 8 + u) * 4096 + n0 + nl;
            hT2[toff] = hh; hT2[toff + 2048] = hl;
        }
    }
}

// ---------------------------------------------------------------------------
// Kernel 5: out[b][th][n] = bp[th] + sum_k h[n][b*H+k] * Wp[k][th]
// ---------------------------------------------------------------------------
__global__ __launch_bounds__(256) void head_kernel(const float* __restrict__ h,
                                                   const float* __restrict__ Wp,
                                                   const float* __restrict__ bp,
                                                   float* __restrict__ out) {
    const int idx = blockIdx.x * 256 + threadIdx.x;
    const int b = idx >> 11;
    const int n = idx & (NN - 1);
    float hv[HH];
    const float* hp = h + (size_t)n * HCOLS + b * HH;
#pragma unroll
    for (int k = 0; k < HH; ++k) hv[k] = hp[k];
#pragma unroll
    for (int th = 0; th < HOR; ++th) {
        float acc = bp[th];
#pragma unroll
        for (int k = 0; k < HH; ++k) acc += hv[k] * Wp[k * HOR + th];
        out[((size_t)b * HOR + th) * NN + n] = acc;
    }
}

// ---------------------------------------------------------------------------
extern "C" void kernel_launch(void* const* d_in, const int* in_sizes, int n_in,
                              void* d_out, int out_size, void* d_ws, size_t ws_size,
                              hipStream_t stream) {
    const float* x  = (const float*)d_in[0];
    const float* E1 = (const float*)d_in[1];
    const float* E2 = (const float*)d_in[2];
    const float* Wx = (const float*)d_in[3];
    const float* bx = (const float*)d_in[4];
    const float* Wh = (const float*)d_in[5];
    const float* bh = (const float*)d_in[6];
    const float* Wp = (const float*)d_in[7];
    const float* bp = (const float*)d_in[8];

    char* ws = (char*)d_ws;
    u16*   A2   = (u16*)(ws);                         // 16 MB  [2048][2][2048]
    u16*   B2   = (u16*)(ws + (16ull << 20));         //  8 MB  [1024][2][2048] (XT, reused as hT)
    float* P    = (float*)(ws + (24ull << 20));       // 16 MB  (2 k-slice partials)
    float* AX   = (float*)(ws + (56ull << 20));       //  8 MB
    float* cst  = (float*)(ws + (64ull << 20));       //  8 MB
    float* h32  = (float*)(ws + (72ull << 20));       //  8 MB
    float* Whr  = (float*)(ws + (80ull << 20));       // 16 KB
    float* Wxr  = (float*)(ws + (80ull << 20) + 65536);
    float* bfold= (float*)(ws + (80ull << 20) + 131072);

    adj_softmax<<<NN, 256, 0, stream>>>(E1, E2, A2);
    transpose_x<<<(XCOLS * NN) / 256, 256, 0, stream>>>(x, B2);
    prep_weights<<<1, 256, 0, stream>>>(Wx, bx, Wh, bh, Whr, Wxr, bfold);

    dim3 gg(HCOLS / 64, NN / 128, KSPLIT);   // 16 x 16 x 2 = 512 blocks
    gemm3d<<<gg, 256, 0, stream>>>(A2, B2, P);
    reduce_ax<<<(int)(CSZ / 4 / 256), 256, 0, stream>>>(P, AX);

    for (int t = 0; t < TT; ++t) {
        if (t > 0)
            gemm3d<<<gg, 256, 0, stream>>>(A2, B2, P);
        gate_update<<<dim3(NN / 64, BB / 4), 256, 0, stream>>>(AX, P, Whr, Wxr, bfold,
                                                               cst, h32, B2, t, t == 0 ? 1 : 0);
    }

    head_kernel<<<(BB * NN) / 256, 256, 0, stream>>>(h32, Wp, bp, (float*)d_out);
}

// Round 7
// 1142.404 us; speedup vs baseline: 1.7986x; 1.7986x over previous
//
#include <hip/hip_runtime.h>
#include <hip/hip_bf16.h>
#include <cstddef>
#include <cstdint>

#define NN 2048      // nodes (M and K of the big GEMMs)
#define CIN 2
#define HH 32        // hidden
#define EMB 16
#define HOR 12
#define BB 32        // batch
#define TT 16        // time steps
#define GC 128       // 4*HH gate channels
#define XCOLS 1024   // B*T*C
#define HCOLS 1024   // B*H  (GEMM N dim)
#define KSPLIT 2
#define KS (NN / KSPLIT)          // 1024 per k-slice
#define NIT (KS / 32)             // 32 K-iterations (BK=32)
#define CSZ ((size_t)NN * HCOLS)  // one partial C: 2M floats

typedef __attribute__((ext_vector_type(8))) _Float16 f16x8;
typedef __attribute__((ext_vector_type(16))) float f32x16;
typedef unsigned short u16;

// ---------------------------------------------------------------------------
// Kernel 1: A = softmax(relu(E1 @ E2^T)) -> A2 fp16 [row][k]
// ---------------------------------------------------------------------------
__global__ __launch_bounds__(256) void adj_softmax(const float* __restrict__ E1,
                                                   const float* __restrict__ E2,
                                                   _Float16* __restrict__ A2) {
    const int i = blockIdx.x;
    __shared__ float red[256];
    float e1[EMB];
#pragma unroll
    for (int k = 0; k < EMB; ++k) e1[k] = E1[i * EMB + k];

    float s[8];
    float mx = -1e30f;
#pragma unroll
    for (int q = 0; q < 8; ++q) {
        const int j = q * 256 + threadIdx.x;
        float d = 0.f;
#pragma unroll
        for (int k = 0; k < EMB; ++k) d += e1[k] * E2[j * EMB + k];
        d = fmaxf(d, 0.0f);
        s[q] = d;
        mx = fmaxf(mx, d);
    }
    red[threadIdx.x] = mx;
    __syncthreads();
    for (int off = 128; off > 0; off >>= 1) {
        if (threadIdx.x < off) red[threadIdx.x] = fmaxf(red[threadIdx.x], red[threadIdx.x + off]);
        __syncthreads();
    }
    mx = red[0];
    __syncthreads();

    float sum = 0.f;
#pragma unroll
    for (int q = 0; q < 8; ++q) { s[q] = expf(s[q] - mx); sum += s[q]; }
    red[threadIdx.x] = sum;
    __syncthreads();
    for (int off = 128; off > 0; off >>= 1) {
        if (threadIdx.x < off) red[threadIdx.x] += red[threadIdx.x + off];
        __syncthreads();
    }
    const float inv = 1.0f / red[0];
#pragma unroll
    for (int q = 0; q < 8; ++q)
        A2[(size_t)i * NN + q * 256 + threadIdx.x] = (_Float16)(s[q] * inv);
}

// ---------------------------------------------------------------------------
// Kernel 2: B2x[col][s][node] fp16 hi/lo split of x (col = (b*T+t)*C + c).
// lo = residual; normal-range for |x|>0.12, subnormal loss <=6e-5 - harmless.
// ---------------------------------------------------------------------------
__global__ __launch_bounds__(256) void transpose_x(const float* __restrict__ x,
                                                   _Float16* __restrict__ B2x) {
    const int idx = blockIdx.x * 256 + threadIdx.x;
    const int col = idx >> 11;
    const int j   = idx & (NN - 1);
    const int bt  = col >> 1;
    const int c   = col & 1;
    const float v = x[((size_t)bt * NN + j) * CIN + c];
    const _Float16 hi = (_Float16)v;
    const _Float16 lo = (_Float16)(v - (float)hi);
    const size_t base = (size_t)col * 4096 + j;
    B2x[base] = hi; B2x[base + 2048] = lo;
}

// ---------------------------------------------------------------------------
// Kernel 3: fp16 MFMA GEMM (32x32x16), software-pipelined LDS double-buffer.
// Cp[z][2048][1024] = A[.][z-slice] * B[z-slice][.]   (z = blockIdx.z)
// NPROD=1: C = A*B (B single fp16 plane, stride 2048) - recurrent path.
// NPROD=2: C = A*Bhi + A*Blo (B stride 4096)          - x path.
// Block 128x64, 4 waves each 64x32 (2 acc tiles of 32x32x16_f16), BK=32.
// LDS/buf: A [ko4][row128][16B]=8KB, B [s][ko4][col64][16B]=4KB*NPROD.
// ---------------------------------------------------------------------------
template <int NPROD>
__global__ __launch_bounds__(256, 2) void gemm_f16(const _Float16* __restrict__ A2,
                                                   const _Float16* __restrict__ B2,
                                                   float* __restrict__ Cp) {
    constexpr int BSTR = 2048 * NPROD;            // B row stride (elements)
    constexpr int BUF  = 8192 + NPROD * 4096;     // bytes per LDS buffer
    __shared__ char smem[2 * BUF];
    const int tid  = threadIdx.x;
    const int w    = tid >> 6;
    const int lane = tid & 63;
    const int m0 = blockIdx.y * 128;
    const int n0 = blockIdx.x * 64;
    const int k0 = blockIdx.z * KS;

    // ---- staging: chunks cid = tid + j*256. j<2: A (512 chunks); j>=2: B.
    const _Float16 *gpa, *gpb, *gpc, *gpd = nullptr;
    int lda, ldb, ldc, ldd = 0;
    {
        int cid, ko, row;
        cid = tid;              ko = cid >> 7; row = cid & 127;
        gpa = A2 + (size_t)(m0 + row) * 2048 + k0 + ko * 8;
        lda = ko * 2048 + row * 16;
        cid = tid + 256;        ko = cid >> 7; row = cid & 127;
        gpb = A2 + (size_t)(m0 + row) * 2048 + k0 + ko * 8;
        ldb = ko * 2048 + row * 16;
        // B chunk j=2: cid2 = tid (s=0)
        const int ko2 = (tid >> 6) & 3, col2 = tid & 63;
        gpc = B2 + (size_t)(n0 + col2) * BSTR + k0 + ko2 * 8;
        ldc = 8192 + ko2 * 1024 + col2 * 16;
        if constexpr (NPROD == 2) {   // B chunk j=3: s=1
            gpd = B2 + (size_t)(n0 + col2) * BSTR + 2048 + k0 + ko2 * 8;
            ldd = 8192 + 4096 + ko2 * 1024 + col2 * 16;
        }
    }

    // ---- fragment offsets: wave (wr,wc); lane: lrow = lane&31, lg = lane>>5
    const int lrow = lane & 31, lg = lane >> 5;
    const int wr = (w >> 1) * 64;
    const int wc = (w & 1) * 32;
    const int aoff00 = (0 * 2 + lg) * 2048 + (wr +  0 + lrow) * 16;  // [i=0][ks=0]
    const int aoff01 = (1 * 2 + lg) * 2048 + (wr +  0 + lrow) * 16;  // [i=0][ks=1]
    const int aoff10 = (0 * 2 + lg) * 2048 + (wr + 32 + lrow) * 16;  // [i=1][ks=0]
    const int aoff11 = (1 * 2 + lg) * 2048 + (wr + 32 + lrow) * 16;  // [i=1][ks=1]
    const int boff0h = 8192 + (0 * 2 + lg) * 1024 + (wc + lrow) * 16;
    const int boff1h = 8192 + (1 * 2 + lg) * 1024 + (wc + lrow) * 16;
    const int boff0l = boff0h + 4096;
    const int boff1l = boff1h + 4096;

    f32x16 acc0 = (f32x16)(0.0f), acc1 = (f32x16)(0.0f);

    uint4 Xa, Xb, Xc, Xd;
    uint4 Ya, Yb, Yc, Yd;

#define LOADSET(A_, B_, C_, D_)                                                \
    A_ = *(const uint4*)gpa; gpa += 32;                                        \
    B_ = *(const uint4*)gpb; gpb += 32;                                        \
    C_ = *(const uint4*)gpc; gpc += 32;                                        \
    if constexpr (NPROD == 2) { D_ = *(const uint4*)gpd; gpd += 32; }

#define STORESET(A_, B_, C_, D_, SB)                                           \
    *(uint4*)((SB) + lda) = A_;                                                \
    *(uint4*)((SB) + ldb) = B_;                                                \
    *(uint4*)((SB) + ldc) = C_;                                                \
    if constexpr (NPROD == 2) { *(uint4*)((SB) + ldd) = D_; }

#define COMPUTE(BUFI) do {                                                     \
    const char* sb = smem + (BUFI) * BUF;                                      \
    f16x8 fa00 = *(const f16x8*)(sb + aoff00);                                 \
    f16x8 fa01 = *(const f16x8*)(sb + aoff01);                                 \
    f16x8 fa10 = *(const f16x8*)(sb + aoff10);                                 \
    f16x8 fa11 = *(const f16x8*)(sb + aoff11);                                 \
    f16x8 fb0h = *(const f16x8*)(sb + boff0h);                                 \
    f16x8 fb1h = *(const f16x8*)(sb + boff1h);                                 \
    acc0 = __builtin_amdgcn_mfma_f32_32x32x16_f16(fa00, fb0h, acc0, 0, 0, 0);  \
    acc1 = __builtin_amdgcn_mfma_f32_32x32x16_f16(fa10, fb0h, acc1, 0, 0, 0);  \
    acc0 = __builtin_amdgcn_mfma_f32_32x32x16_f16(fa01, fb1h, acc0, 0, 0, 0);  \
    acc1 = __builtin_amdgcn_mfma_f32_32x32x16_f16(fa11, fb1h, acc1, 0, 0, 0);  \
    if constexpr (NPROD == 2) {                                                \
        f16x8 fb0l = *(const f16x8*)(sb + boff0l);                             \
        f16x8 fb1l = *(const f16x8*)(sb + boff1l);                             \
        acc0 = __builtin_amdgcn_mfma_f32_32x32x16_f16(fa00, fb0l, acc0, 0, 0, 0); \
        acc1 = __builtin_amdgcn_mfma_f32_32x32x16_f16(fa10, fb0l, acc1, 0, 0, 0); \
        acc0 = __builtin_amdgcn_mfma_f32_32x32x16_f16(fa01, fb1l, acc0, 0, 0, 0); \
        acc1 = __builtin_amdgcn_mfma_f32_32x32x16_f16(fa11, fb1l, acc1, 0, 0, 0); \
    }                                                                          \
} while (0)

    LOADSET(Xa, Xb, Xc, Xd)     // tile 0
    LOADSET(Ya, Yb, Yc, Yd)     // tile 1
#pragma unroll 1
    for (int it = 0; it < NIT; it += 2) {
        STORESET(Xa, Xb, Xc, Xd, smem)          // waits vmcnt on X (issued 1 iter ago)
        __syncthreads();
        LOADSET(Xa, Xb, Xc, Xd)                 // tile it+2 (over-read past slice: harmless, in-ws)
        COMPUTE(0);
        STORESET(Ya, Yb, Yc, Yd, smem + BUF)
        __syncthreads();
        LOADSET(Ya, Yb, Yc, Yd)                 // tile it+3
        COMPUTE(1);
    }
#undef LOADSET
#undef STORESET
#undef COMPUTE

    // ---- epilogue: 32x32 C layout: col=lane&31, row=(r&3)+8*(r>>2)+4*lg ----
    float* Cs = Cp + (size_t)blockIdx.z * CSZ;
    const int colb = n0 + wc + lrow;
#pragma unroll
    for (int r = 0; r < 16; ++r) {
        const int rp = (r & 3) + 8 * (r >> 2) + 4 * lg;
        Cs[(size_t)(m0 + wr + rp) * HCOLS + colb]      = acc0[r];
        Cs[(size_t)(m0 + wr + 32 + rp) * HCOLS + colb] = acc1[r];
    }
}

// ---------------------------------------------------------------------------
// Kernel 3b: AX = sum of KSPLIT k-slice partials (one-time, x path)
// ---------------------------------------------------------------------------
__global__ __launch_bounds__(256) void reduce_ax(const float* __restrict__ P,
                                                 float* __restrict__ AX) {
    const size_t idx = (size_t)blockIdx.x * 256 + threadIdx.x;
    const float4* P4 = (const float4*)P;
    const size_t q = CSZ / 4;
    float4 a = P4[idx], b = P4[idx + q];
    float4 r;
    r.x = a.x + b.x;
    r.y = a.y + b.y;
    r.z = a.z + b.z;
    r.w = a.w + b.w;
    ((float4*)AX)[idx] = r;
}

// ---------------------------------------------------------------------------
// Kernel 3c: weight prep. Whr[k][h][g] = Wh[k][g*32+h]; Wxr[c][h][g]; bfold.
// ---------------------------------------------------------------------------
__global__ __launch_bounds__(256) void prep_weights(const float* __restrict__ Wx,
                                                    const float* __restrict__ bx,
                                                    const float* __restrict__ Wh,
                                                    const float* __restrict__ bh,
                                                    float* __restrict__ Whr,
                                                    float* __restrict__ Wxr,
                                                    float* __restrict__ bfold) {
    const int tid = threadIdx.x;
#pragma unroll
    for (int r = 0; r < 16; ++r) {
        const int idx = tid * 16 + r;           // 4096
        const int k = idx >> 7, rem = idx & 127;
        const int h = rem >> 2, g = rem & 3;
        Whr[idx] = Wh[k * GC + g * HH + h];
    }
    {
        const int idx = tid;                    // 256
        const int c = idx >> 7, rem = idx & 127;
        const int h = rem >> 2, g = rem & 3;
        Wxr[idx] = Wx[c * GC + g * HH + h];
    }
    if (tid < 128) {
        const int h = tid >> 2, g = tid & 3;
        bfold[tid] = bx[g * HH + h] + bh[g * HH + h];
    }
}

// ---------------------------------------------------------------------------
// Kernel 4: gates + cell update, 64 nodes x 4 batches per block.
// Reads KSPLIT k-slice partials inline; writes h32 and hT (fp16 [col][node]).
// ---------------------------------------------------------------------------
__global__ __launch_bounds__(256) void gate_update(const float* __restrict__ AX,
                                                   const float* __restrict__ Ahp,
                                                   const float* __restrict__ Whr,
                                                   const float* __restrict__ Wxr,
                                                   const float* __restrict__ bfold,
                                                   float* __restrict__ c,
                                                   float* __restrict__ h32,
                                                   _Float16* __restrict__ hT,
                                                   int t, int first) {
    const int n0 = blockIdx.x * 64;
    const int b0 = blockIdx.y * 4;
    const int tid = threadIdx.x;
    __shared__ float whr[4096];
    __shared__ float wxr[256];
    __shared__ float bfl[128];
    __shared__ float ah_s[64][33];
    __shared__ float axs[2][64];

#pragma unroll
    for (int r = 0; r < 4; ++r)
        *(float4*)&whr[(tid * 4 + r * 1024)] = *(const float4*)&Whr[(tid * 4 + r * 1024)];
    if (tid < 64)  *(float4*)&wxr[tid * 4] = *(const float4*)&Wxr[tid * 4];
    if (tid < 32)  *(float4*)&bfl[tid * 4] = *(const float4*)&bfold[tid * 4];

    const int nl = tid & 63;
    const int hq = tid >> 6;

#pragma unroll 1
    for (int bi = 0; bi < 4; ++bi) {
        const int b = b0 + bi;
        if (bi) __syncthreads();

        if (!first) {
            const int nls = tid >> 2;
            const int kq = (tid & 3) * 8;
            float4 a0 = make_float4(0, 0, 0, 0), a1 = make_float4(0, 0, 0, 0);
#pragma unroll
            for (int s = 0; s < KSPLIT; ++s) {
                const float* src = Ahp + s * CSZ + (size_t)(n0 + nls) * HCOLS + b * HH + kq;
                const float4 v0 = *(const float4*)src;
                const float4 v1 = *(const float4*)(src + 4);
                a0.x += v0.x; a0.y += v0.y; a0.z += v0.z; a0.w += v0.w;
                a1.x += v1.x; a1.y += v1.y; a1.z += v1.z; a1.w += v1.w;
            }
            ah_s[nls][kq + 0] = a0.x; ah_s[nls][kq + 1] = a0.y;
            ah_s[nls][kq + 2] = a0.z; ah_s[nls][kq + 3] = a0.w;
            ah_s[nls][kq + 4] = a1.x; ah_s[nls][kq + 5] = a1.y;
            ah_s[nls][kq + 6] = a1.z; ah_s[nls][kq + 7] = a1.w;
        }
        if (tid < 128) {
            const int which = tid >> 6, nls = tid & 63;
            axs[which][nls] = AX[(size_t)(n0 + nls) * XCOLS + (b * TT + t) * CIN + which];
        }
        __syncthreads();

        const float ax0 = axs[0][nl], ax1 = axs[1][nl];
        float acc[8][4];
#pragma unroll
        for (int u = 0; u < 8; ++u) {
            const int h = hq * 8 + u;
#pragma unroll
            for (int g = 0; g < 4; ++g)
                acc[u][g] = bfl[h * 4 + g] + ax0 * wxr[h * 4 + g] + ax1 * wxr[128 + h * 4 + g];
        }
        if (!first) {
            float ah_r[HH];
#pragma unroll
            for (int k = 0; k < HH; ++k) ah_r[k] = ah_s[nl][k];
#pragma unroll 4
            for (int k = 0; k < HH; ++k) {
                const float a = ah_r[k];
#pragma unroll
                for (int u = 0; u < 8; ++u) {
                    const float* wp = &whr[(k * HH + hq * 8 + u) * 4];
                    acc[u][0] += a * wp[0];
                    acc[u][1] += a * wp[1];
                    acc[u][2] += a * wp[2];
                    acc[u][3] += a * wp[3];
                }
            }
        }

        float cn[8], hn[8];
        const size_t off = (size_t)(n0 + nl) * HCOLS + b * HH + hq * 8;
        float4 c0o = make_float4(0, 0, 0, 0), c1o = make_float4(0, 0, 0, 0);
        if (!first) { c0o = *(const float4*)(c + off); c1o = *(const float4*)(c + off + 4); }
        const float cold[8] = {c0o.x, c0o.y, c0o.z, c0o.w, c1o.x, c1o.y, c1o.z, c1o.w};
#pragma unroll
        for (int u = 0; u < 8; ++u) {
            const float i_ = 1.0f / (1.0f + expf(-acc[u][0]));
            const float f_ = 1.0f / (1.0f + expf(-acc[u][1]));
            const float o_ = 1.0f / (1.0f + expf(-acc[u][2]));
            const float g_ = tanhf(acc[u][3]);
            const float c_t = f_ * cold[u] + i_ * g_;
            cn[u] = c_t;
            hn[u] = o_ * tanhf(c_t);
        }
        *(float4*)(c + off)       = make_float4(cn[0], cn[1], cn[2], cn[3]);
        *(float4*)(c + off + 4)   = make_float4(cn[4], cn[5], cn[6], cn[7]);
        *(float4*)(h32 + off)     = make_float4(hn[0], hn[1], hn[2], hn[3]);
        *(float4*)(h32 + off + 4) = make_float4(hn[4], hn[5], hn[6], hn[7]);
#pragma unroll
        for (int u = 0; u < 8; ++u)
            hT[(size_t)(b * HH + hq * 8 + u) * 2048 + n0 + nl] = (_Float16)hn[u];
    }
}

// ---------------------------------------------------------------------------
// Kernel 5: out[b][th][n] = bp[th] + sum_k h[n][b*H+k] * Wp[k][th]
// ---------------------------------------------------------------------------
__global__ __launch_bounds__(256) void head_kernel(const float* __restrict__ h,
                                                   const float* __restrict__ Wp,
                                                   const float* __restrict__ bp,
                                                   float* __restrict__ out) {
    const int idx = blockIdx.x * 256 + threadIdx.x;
    const int b = idx >> 11;
    const int n = idx & (NN - 1);
    float hv[HH];
    const float* hp = h + (size_t)n * HCOLS + b * HH;
#pragma unroll
    for (int k = 0; k < HH; ++k) hv[k] = hp[k];
#pragma unroll
    for (int th = 0; th < HOR; ++th) {
        float acc = bp[th];
#pragma unroll
        for (int k = 0; k < HH; ++k) acc += hv[k] * Wp[k * HOR + th];
        out[((size_t)b * HOR + th) * NN + n] = acc;
    }
}

// ---------------------------------------------------------------------------
extern "C" void kernel_launch(void* const* d_in, const int* in_sizes, int n_in,
                              void* d_out, int out_size, void* d_ws, size_t ws_size,
                              hipStream_t stream) {
    const float* x  = (const float*)d_in[0];
    const float* E1 = (const float*)d_in[1];
    const float* E2 = (const float*)d_in[2];
    const float* Wx = (const float*)d_in[3];
    const float* bx = (const float*)d_in[4];
    const float* Wh = (const float*)d_in[5];
    const float* bh = (const float*)d_in[6];
    const float* Wp = (const float*)d_in[7];
    const float* bp = (const float*)d_in[8];

    char* ws = (char*)d_ws;
    _Float16* A2  = (_Float16*)(ws);                    //  8 MB  [2048][2048]
    _Float16* B2x = (_Float16*)(ws + ( 8ull << 20));    //  8 MB  [1024][2][2048]
    _Float16* hT  = (_Float16*)(ws + (16ull << 20));    //  4 MB  [1024][2048]
    float* P    = (float*)(ws + (24ull << 20));         // 16 MB  (2 k-slice partials)
    float* AX   = (float*)(ws + (40ull << 20));         //  8 MB
    float* cst  = (float*)(ws + (48ull << 20));         //  8 MB
    float* h32  = (float*)(ws + (56ull << 20));         //  8 MB
    float* Whr  = (float*)(ws + (64ull << 20));         // 16 KB
    float* Wxr  = (float*)(ws + (64ull << 20) + 65536);
    float* bfold= (float*)(ws + (64ull << 20) + 131072);

    adj_softmax<<<NN, 256, 0, stream>>>(E1, E2, A2);
    transpose_x<<<(XCOLS * NN) / 256, 256, 0, stream>>>(x, B2x);
    prep_weights<<<1, 256, 0, stream>>>(Wx, bx, Wh, bh, Whr, Wxr, bfold);

    dim3 gg(HCOLS / 64, NN / 128, KSPLIT);   // 16 x 16 x 2 = 512 blocks
    gemm_f16<2><<<gg, 256, 0, stream>>>(A2, B2x, P);     // x path: 2-product
    reduce_ax<<<(int)(CSZ / 4 / 256), 256, 0, stream>>>(P, AX);

    for (int t = 0; t < TT; ++t) {
        if (t > 0)
            gemm_f16<1><<<gg, 256, 0, stream>>>(A2, hT, P);   // recurrent: 1-product
        gate_update<<<dim3(NN / 64, BB / 4), 256, 0, stream>>>(AX, P, Whr, Wxr, bfold,
                                                               cst, h32, hT, t, t == 0 ? 1 : 0);
    }

    head_kernel<<<(BB * NN) / 256, 256, 0, stream>>>(h32, Wp, bp, (float*)d_out);
}

// Round 8
// 1083.429 us; speedup vs baseline: 1.8965x; 1.0544x over previous
//
#include <hip/hip_runtime.h>
#include <hip/hip_bf16.h>
#include <cstddef>
#include <cstdint>

#define NN 2048      // nodes (M and K of the big GEMMs)
#define CIN 2
#define HH 32        // hidden
#define EMB 16
#define HOR 12
#define BB 32        // batch
#define TT 16        // time steps
#define GC 128       // 4*HH gate channels
#define XCOLS 1024   // B*T*C
#define HCOLS 1024   // B*H  (GEMM N dim)
#define KSPLIT 4
#define KS (NN / KSPLIT)          // 512 per k-slice
#define NIT (KS / 32)             // 16 K-iterations (BK=32)
#define CSZ ((size_t)NN * HCOLS)  // one partial C: 2M floats

typedef __attribute__((ext_vector_type(8))) _Float16 f16x8;
typedef __attribute__((ext_vector_type(16))) float f32x16;
typedef unsigned short u16;

// ---------------------------------------------------------------------------
// Kernel 1: A = softmax(relu(E1 @ E2^T)) -> A2 fp16 [row][k]
// ---------------------------------------------------------------------------
__global__ __launch_bounds__(256) void adj_softmax(const float* __restrict__ E1,
                                                   const float* __restrict__ E2,
                                                   _Float16* __restrict__ A2) {
    const int i = blockIdx.x;
    __shared__ float red[256];
    float e1[EMB];
#pragma unroll
    for (int k = 0; k < EMB; ++k) e1[k] = E1[i * EMB + k];

    float s[8];
    float mx = -1e30f;
#pragma unroll
    for (int q = 0; q < 8; ++q) {
        const int j = q * 256 + threadIdx.x;
        float d = 0.f;
#pragma unroll
        for (int k = 0; k < EMB; ++k) d += e1[k] * E2[j * EMB + k];
        d = fmaxf(d, 0.0f);
        s[q] = d;
        mx = fmaxf(mx, d);
    }
    red[threadIdx.x] = mx;
    __syncthreads();
    for (int off = 128; off > 0; off >>= 1) {
        if (threadIdx.x < off) red[threadIdx.x] = fmaxf(red[threadIdx.x], red[threadIdx.x + off]);
        __syncthreads();
    }
    mx = red[0];
    __syncthreads();

    float sum = 0.f;
#pragma unroll
    for (int q = 0; q < 8; ++q) { s[q] = expf(s[q] - mx); sum += s[q]; }
    red[threadIdx.x] = sum;
    __syncthreads();
    for (int off = 128; off > 0; off >>= 1) {
        if (threadIdx.x < off) red[threadIdx.x] += red[threadIdx.x + off];
        __syncthreads();
    }
    const float inv = 1.0f / red[0];
#pragma unroll
    for (int q = 0; q < 8; ++q)
        A2[(size_t)i * NN + q * 256 + threadIdx.x] = (_Float16)(s[q] * inv);
}

// ---------------------------------------------------------------------------
// Kernel 2: B2x[col][s][node] fp16 hi/lo split of x (col = (b*T+t)*C + c).
// ---------------------------------------------------------------------------
__global__ __launch_bounds__(256) void transpose_x(const float* __restrict__ x,
                                                   _Float16* __restrict__ B2x) {
    const int idx = blockIdx.x * 256 + threadIdx.x;
    const int col = idx >> 11;
    const int j   = idx & (NN - 1);
    const int bt  = col >> 1;
    const int c   = col & 1;
    const float v = x[((size_t)bt * NN + j) * CIN + c];
    const _Float16 hi = (_Float16)v;
    const _Float16 lo = (_Float16)(v - (float)hi);
    const size_t base = (size_t)col * 4096 + j;
    B2x[base] = hi; B2x[base + 2048] = lo;
}

// ---------------------------------------------------------------------------
// Kernel 3: fp16 MFMA GEMM (32x32x16), pipelined LDS double-buffer.
// Cp[z][2048][1024] = A[.][z-slice] * B[z-slice][.]   (z = blockIdx.z)
// NPROD=1: C = A*B (B stride 2048)        - recurrent path.
// NPROD=2: C = A*Bhi + A*Blo (stride 4096)- x path.
// Block 128x128, 4 waves each 64x64 (2x2 accs of 32x32), BK=32, KSPLIT=4.
// LDS/buf: A [ko4][row128][16B]=8KB, B same per plane. Conflict-free.
// ---------------------------------------------------------------------------
template <int NPROD>
__global__ __launch_bounds__(256, 2) void gemm_f16(const _Float16* __restrict__ A2,
                                                   const _Float16* __restrict__ B2,
                                                   float* __restrict__ Cp) {
    constexpr int BSTR = 2048 * NPROD;            // B row stride (elements)
    constexpr int BUF  = 8192 + NPROD * 8192;     // bytes per LDS buffer
    __shared__ char smem[2 * BUF];
    const int tid  = threadIdx.x;
    const int w    = tid >> 6;
    const int lane = tid & 63;
    const int m0 = blockIdx.y * 128;
    const int n0 = blockIdx.x * 128;
    const int k0 = blockIdx.z * KS;

    // ---- staging: A 512 chunks (cid=tid, tid+256), B same; lo plane extra.
    const _Float16 *gpa0, *gpa1, *gpb0, *gpb1, *gpc0 = nullptr, *gpc1 = nullptr;
    int lda0, lda1, ldb0, ldb1, ldc0 = 0, ldc1 = 0;
    {
        int cid, ko, row;
        cid = tid;       ko = cid >> 7; row = cid & 127;
        gpa0 = A2 + (size_t)(m0 + row) * 2048 + k0 + ko * 8;
        lda0 = ko * 2048 + row * 16;
        cid = tid + 256; ko = cid >> 7; row = cid & 127;
        gpa1 = A2 + (size_t)(m0 + row) * 2048 + k0 + ko * 8;
        lda1 = ko * 2048 + row * 16;
        cid = tid;       ko = cid >> 7; row = cid & 127;
        gpb0 = B2 + (size_t)(n0 + row) * BSTR + k0 + ko * 8;
        ldb0 = 8192 + ko * 2048 + row * 16;
        cid = tid + 256; ko = cid >> 7; row = cid & 127;
        gpb1 = B2 + (size_t)(n0 + row) * BSTR + k0 + ko * 8;
        ldb1 = 8192 + ko * 2048 + row * 16;
        if constexpr (NPROD == 2) {
            gpc0 = gpb0 + 2048; ldc0 = ldb0 + 8192;
            gpc1 = gpb1 + 2048; ldc1 = ldb1 + 8192;
        }
    }

    // ---- fragment offsets: wave (wr,wc); lane: lrow = lane&31, lg = lane>>5
    const int lrow = lane & 31, lg = lane >> 5;
    const int wr = (w >> 1) * 64;
    const int wc = (w & 1) * 64;
    const int aoff00 = (0 * 2 + lg) * 2048 + (wr +  0 + lrow) * 16;  // i=0 ks=0
    const int aoff01 = (1 * 2 + lg) * 2048 + (wr +  0 + lrow) * 16;  // i=0 ks=1
    const int aoff10 = (0 * 2 + lg) * 2048 + (wr + 32 + lrow) * 16;  // i=1 ks=0
    const int aoff11 = (1 * 2 + lg) * 2048 + (wr + 32 + lrow) * 16;  // i=1 ks=1
    const int boff00 = 8192 + (0 * 2 + lg) * 2048 + (wc +  0 + lrow) * 16;
    const int boff01 = 8192 + (1 * 2 + lg) * 2048 + (wc +  0 + lrow) * 16;
    const int boff10 = 8192 + (0 * 2 + lg) * 2048 + (wc + 32 + lrow) * 16;
    const int boff11 = 8192 + (1 * 2 + lg) * 2048 + (wc + 32 + lrow) * 16;

    f32x16 acc00 = (f32x16)(0.0f), acc01 = (f32x16)(0.0f);
    f32x16 acc10 = (f32x16)(0.0f), acc11 = (f32x16)(0.0f);

    uint4 Xa0, Xa1, Xb0, Xb1, Xc0, Xc1;
    uint4 Ya0, Ya1, Yb0, Yb1, Yc0, Yc1;

#define LOADSET(P)                                                             \
    P##a0 = *(const uint4*)gpa0; gpa0 += 32;                                   \
    P##a1 = *(const uint4*)gpa1; gpa1 += 32;                                   \
    P##b0 = *(const uint4*)gpb0; gpb0 += 32;                                   \
    P##b1 = *(const uint4*)gpb1; gpb1 += 32;                                   \
    if constexpr (NPROD == 2) {                                                \
        P##c0 = *(const uint4*)gpc0; gpc0 += 32;                               \
        P##c1 = *(const uint4*)gpc1; gpc1 += 32;                               \
    }

#define STORESET(P, SB)                                                        \
    *(uint4*)((SB) + lda0) = P##a0;                                            \
    *(uint4*)((SB) + lda1) = P##a1;                                            \
    *(uint4*)((SB) + ldb0) = P##b0;                                            \
    *(uint4*)((SB) + ldb1) = P##b1;                                            \
    if constexpr (NPROD == 2) {                                                \
        *(uint4*)((SB) + ldc0) = P##c0;                                        \
        *(uint4*)((SB) + ldc1) = P##c1;                                        \
    }

#define COMPUTE(BUFI) do {                                                     \
    const char* sb = smem + (BUFI) * BUF;                                      \
    f16x8 fa00 = *(const f16x8*)(sb + aoff00);                                 \
    f16x8 fa01 = *(const f16x8*)(sb + aoff01);                                 \
    f16x8 fa10 = *(const f16x8*)(sb + aoff10);                                 \
    f16x8 fa11 = *(const f16x8*)(sb + aoff11);                                 \
    f16x8 fb00 = *(const f16x8*)(sb + boff00);                                 \
    f16x8 fb01 = *(const f16x8*)(sb + boff01);                                 \
    f16x8 fb10 = *(const f16x8*)(sb + boff10);                                 \
    f16x8 fb11 = *(const f16x8*)(sb + boff11);                                 \
    acc00 = __builtin_amdgcn_mfma_f32_32x32x16_f16(fa00, fb00, acc00, 0, 0, 0);\
    acc01 = __builtin_amdgcn_mfma_f32_32x32x16_f16(fa00, fb10, acc01, 0, 0, 0);\
    acc10 = __builtin_amdgcn_mfma_f32_32x32x16_f16(fa10, fb00, acc10, 0, 0, 0);\
    acc11 = __builtin_amdgcn_mfma_f32_32x32x16_f16(fa10, fb10, acc11, 0, 0, 0);\
    acc00 = __builtin_amdgcn_mfma_f32_32x32x16_f16(fa01, fb01, acc00, 0, 0, 0);\
    acc01 = __builtin_amdgcn_mfma_f32_32x32x16_f16(fa01, fb11, acc01, 0, 0, 0);\
    acc10 = __builtin_amdgcn_mfma_f32_32x32x16_f16(fa11, fb01, acc10, 0, 0, 0);\
    acc11 = __builtin_amdgcn_mfma_f32_32x32x16_f16(fa11, fb11, acc11, 0, 0, 0);\
    if constexpr (NPROD == 2) {                                                \
        f16x8 fc00 = *(const f16x8*)(sb + boff00 + 8192);                      \
        f16x8 fc01 = *(const f16x8*)(sb + boff01 + 8192);                      \
        f16x8 fc10 = *(const f16x8*)(sb + boff10 + 8192);                      \
        f16x8 fc11 = *(const f16x8*)(sb + boff11 + 8192);                      \
        acc00 = __builtin_amdgcn_mfma_f32_32x32x16_f16(fa00, fc00, acc00, 0, 0, 0); \
        acc01 = __builtin_amdgcn_mfma_f32_32x32x16_f16(fa00, fc10, acc01, 0, 0, 0); \
        acc10 = __builtin_amdgcn_mfma_f32_32x32x16_f16(fa10, fc00, acc10, 0, 0, 0); \
        acc11 = __builtin_amdgcn_mfma_f32_32x32x16_f16(fa10, fc10, acc11, 0, 0, 0); \
        acc00 = __builtin_amdgcn_mfma_f32_32x32x16_f16(fa01, fc01, acc00, 0, 0, 0); \
        acc01 = __builtin_amdgcn_mfma_f32_32x32x16_f16(fa01, fc11, acc01, 0, 0, 0); \
        acc10 = __builtin_amdgcn_mfma_f32_32x32x16_f16(fa11, fc01, acc10, 0, 0, 0); \
        acc11 = __builtin_amdgcn_mfma_f32_32x32x16_f16(fa11, fc11, acc11, 0, 0, 0); \
    }                                                                          \
} while (0)

    LOADSET(X)     // tile 0
    LOADSET(Y)     // tile 1
#pragma unroll 1
    for (int it = 0; it < NIT; it += 2) {
        STORESET(X, smem)                       // waits vmcnt on X
        __syncthreads();
        LOADSET(X)                              // tile it+2 (tail over-read stays in-ws)
        COMPUTE(0);
        STORESET(Y, smem + BUF)
        __syncthreads();
        LOADSET(Y)                              // tile it+3
        COMPUTE(1);
    }
#undef LOADSET
#undef STORESET
#undef COMPUTE

    // ---- epilogue: 32x32 C layout: col=lane&31, row=(r&3)+8*(r>>2)+4*lg ----
    float* Cs = Cp + (size_t)blockIdx.z * CSZ;
    const int col0 = n0 + wc + lrow;
#pragma unroll
    for (int r = 0; r < 16; ++r) {
        const int rp = (r & 3) + 8 * (r >> 2) + 4 * lg;
        Cs[(size_t)(m0 + wr + rp) * HCOLS + col0]           = acc00[r];
        Cs[(size_t)(m0 + wr + rp) * HCOLS + col0 + 32]      = acc01[r];
        Cs[(size_t)(m0 + wr + 32 + rp) * HCOLS + col0]      = acc10[r];
        Cs[(size_t)(m0 + wr + 32 + rp) * HCOLS + col0 + 32] = acc11[r];
    }
}

// ---------------------------------------------------------------------------
// Kernel 3b: AX = sum of KSPLIT k-slice partials (one-time, x path)
// ---------------------------------------------------------------------------
__global__ __launch_bounds__(256) void reduce_ax(const float* __restrict__ P,
                                                 float* __restrict__ AX) {
    const size_t idx = (size_t)blockIdx.x * 256 + threadIdx.x;
    const float4* P4 = (const float4*)P;
    const size_t q = CSZ / 4;
    float4 a = P4[idx], b = P4[idx + q], c = P4[idx + 2 * q], d = P4[idx + 3 * q];
    float4 r;
    r.x = a.x + b.x + c.x + d.x;
    r.y = a.y + b.y + c.y + d.y;
    r.z = a.z + b.z + c.z + d.z;
    r.w = a.w + b.w + c.w + d.w;
    ((float4*)AX)[idx] = r;
}

// ---------------------------------------------------------------------------
// Kernel 3c: weight prep. Whr[k][h][g] = Wh[k][g*32+h]; Wxr[c][h][g]; bfold.
// ---------------------------------------------------------------------------
__global__ __launch_bounds__(256) void prep_weights(const float* __restrict__ Wx,
                                                    const float* __restrict__ bx,
                                                    const float* __restrict__ Wh,
                                                    const float* __restrict__ bh,
                                                    float* __restrict__ Whr,
                                                    float* __restrict__ Wxr,
                                                    float* __restrict__ bfold) {
    const int tid = threadIdx.x;
#pragma unroll
    for (int r = 0; r < 16; ++r) {
        const int idx = tid * 16 + r;           // 4096
        const int k = idx >> 7, rem = idx & 127;
        const int h = rem >> 2, g = rem & 3;
        Whr[idx] = Wh[k * GC + g * HH + h];
    }
    {
        const int idx = tid;                    // 256
        const int c = idx >> 7, rem = idx & 127;
        const int h = rem >> 2, g = rem & 3;
        Wxr[idx] = Wx[c * GC + g * HH + h];
    }
    if (tid < 128) {
        const int h = tid >> 2, g = tid & 3;
        bfold[tid] = bx[g * HH + h] + bh[g * HH + h];
    }
}

// ---------------------------------------------------------------------------
// Kernel 4: gates + cell update, 64 nodes x 4 batches per block.
// Reads KSPLIT k-slice partials inline; writes h32 and hT (fp16 [col][node]).
// ---------------------------------------------------------------------------
__global__ __launch_bounds__(256) void gate_update(const float* __restrict__ AX,
                                                   const float* __restrict__ Ahp,
                                                   const float* __restrict__ Whr,
                                                   const float* __restrict__ Wxr,
                                                   const float* __restrict__ bfold,
                                                   float* __restrict__ c,
                                                   float* __restrict__ h32,
                                                   _Float16* __restrict__ hT,
                                                   int t, int first) {
    const int n0 = blockIdx.x * 64;
    const int b0 = blockIdx.y * 4;
    const int tid = threadIdx.x;
    __shared__ float whr[4096];
    __shared__ float wxr[256];
    __shared__ float bfl[128];
    __shared__ float ah_s[64][33];
    __shared__ float axs[2][64];

#pragma unroll
    for (int r = 0; r < 4; ++r)
        *(float4*)&whr[(tid * 4 + r * 1024)] = *(const float4*)&Whr[(tid * 4 + r * 1024)];
    if (tid < 64)  *(float4*)&wxr[tid * 4] = *(const float4*)&Wxr[tid * 4];
    if (tid < 32)  *(float4*)&bfl[tid * 4] = *(const float4*)&bfold[tid * 4];

    const int nl = tid & 63;
    const int hq = tid >> 6;

#pragma unroll 1
    for (int bi = 0; bi < 4; ++bi) {
        const int b = b0 + bi;
        if (bi) __syncthreads();

        if (!first) {
            const int nls = tid >> 2;
            const int kq = (tid & 3) * 8;
            float4 a0 = make_float4(0, 0, 0, 0), a1 = make_float4(0, 0, 0, 0);
#pragma unroll
            for (int s = 0; s < KSPLIT; ++s) {
                const float* src = Ahp + s * CSZ + (size_t)(n0 + nls) * HCOLS + b * HH + kq;
                const float4 v0 = *(const float4*)src;
                const float4 v1 = *(const float4*)(src + 4);
                a0.x += v0.x; a0.y += v0.y; a0.z += v0.z; a0.w += v0.w;
                a1.x += v1.x; a1.y += v1.y; a1.z += v1.z; a1.w += v1.w;
            }
            ah_s[nls][kq + 0] = a0.x; ah_s[nls][kq + 1] = a0.y;
            ah_s[nls][kq + 2] = a0.z; ah_s[nls][kq + 3] = a0.w;
            ah_s[nls][kq + 4] = a1.x; ah_s[nls][kq + 5] = a1.y;
            ah_s[nls][kq + 6] = a1.z; ah_s[nls][kq + 7] = a1.w;
        }
        if (tid < 128) {
            const int which = tid >> 6, nls = tid & 63;
            axs[which][nls] = AX[(size_t)(n0 + nls) * XCOLS + (b * TT + t) * CIN + which];
        }
        __syncthreads();

        const float ax0 = axs[0][nl], ax1 = axs[1][nl];
        float acc[8][4];
#pragma unroll
        for (int u = 0; u < 8; ++u) {
            const int h = hq * 8 + u;
#pragma unroll
            for (int g = 0; g < 4; ++g)
                acc[u][g] = bfl[h * 4 + g] + ax0 * wxr[h * 4 + g] + ax1 * wxr[128 + h * 4 + g];
        }
        if (!first) {
            float ah_r[HH];
#pragma unroll
            for (int k = 0; k < HH; ++k) ah_r[k] = ah_s[nl][k];
#pragma unroll 4
            for (int k = 0; k < HH; ++k) {
                const float a = ah_r[k];
#pragma unroll
                for (int u = 0; u < 8; ++u) {
                    const float* wp = &whr[(k * HH + hq * 8 + u) * 4];
                    acc[u][0] += a * wp[0];
                    acc[u][1] += a * wp[1];
                    acc[u][2] += a * wp[2];
                    acc[u][3] += a * wp[3];
                }
            }
        }

        float cn[8], hn[8];
        const size_t off = (size_t)(n0 + nl) * HCOLS + b * HH + hq * 8;
        float4 c0o = make_float4(0, 0, 0, 0), c1o = make_float4(0, 0, 0, 0);
        if (!first) { c0o = *(const float4*)(c + off); c1o = *(const float4*)(c + off + 4); }
        const float cold[8] = {c0o.x, c0o.y, c0o.z, c0o.w, c1o.x, c1o.y, c1o.z, c1o.w};
#pragma unroll
        for (int u = 0; u < 8; ++u) {
            const float i_ = 1.0f / (1.0f + expf(-acc[u][0]));
            const float f_ = 1.0f / (1.0f + expf(-acc[u][1]));
            const float o_ = 1.0f / (1.0f + expf(-acc[u][2]));
            const float g_ = tanhf(acc[u][3]);
            const float c_t = f_ * cold[u] + i_ * g_;
            cn[u] = c_t;
            hn[u] = o_ * tanhf(c_t);
        }
        *(float4*)(c + off)       = make_float4(cn[0], cn[1], cn[2], cn[3]);
        *(float4*)(c + off + 4)   = make_float4(cn[4], cn[5], cn[6], cn[7]);
        *(float4*)(h32 + off)     = make_float4(hn[0], hn[1], hn[2], hn[3]);
        *(float4*)(h32 + off + 4) = make_float4(hn[4], hn[5], hn[6], hn[7]);
#pragma unroll
        for (int u = 0; u < 8; ++u)
            hT[(size_t)(b * HH + hq * 8 + u) * 2048 + n0 + nl] = (_Float16)hn[u];
    }
}

// ---------------------------------------------------------------------------
// Kernel 5: out[b][th][n] = bp[th] + sum_k h[n][b*H+k] * Wp[k][th]
// ---------------------------------------------------------------------------
__global__ __launch_bounds__(256) void head_kernel(const float* __restrict__ h,
                                                   const float* __restrict__ Wp,
                                                   const float* __restrict__ bp,
                                                   float* __restrict__ out) {
    const int idx = blockIdx.x * 256 + threadIdx.x;
    const int b = idx >> 11;
    const int n = idx & (NN - 1);
    float hv[HH];
    const float* hp = h + (size_t)n * HCOLS + b * HH;
#pragma unroll
    for (int k = 0; k < HH; ++k) hv[k] = hp[k];
#pragma unroll
    for (int th = 0; th < HOR; ++th) {
        float acc = bp[th];
#pragma unroll
        for (int k = 0; k < HH; ++k) acc += hv[k] * Wp[k * HOR + th];
        out[((size_t)b * HOR + th) * NN + n] = acc;
    }
}

// ---------------------------------------------------------------------------
extern "C" void kernel_launch(void* const* d_in, const int* in_sizes, int n_in,
                              void* d_out, int out_size, void* d_ws, size_t ws_size,
                              hipStream_t stream) {
    const float* x  = (const float*)d_in[0];
    const float* E1 = (const float*)d_in[1];
    const float* E2 = (const float*)d_in[2];
    const float* Wx = (const float*)d_in[3];
    const float* bx = (const float*)d_in[4];
    const float* Wh = (const float*)d_in[5];
    const float* bh = (const float*)d_in[6];
    const float* Wp = (const float*)d_in[7];
    const float* bp = (const float*)d_in[8];

    char* ws = (char*)d_ws;
    _Float16* A2  = (_Float16*)(ws);                    //  8 MB  [2048][2048]
    _Float16* B2x = (_Float16*)(ws + ( 8ull << 20));    //  8 MB  [1024][2][2048]
    _Float16* hT  = (_Float16*)(ws + (16ull << 20));    //  4 MB  [1024][2048]
    float* P    = (float*)(ws + (20ull << 20));         // 32 MB  (4 k-slice partials)
    float* AX   = (float*)(ws + (52ull << 20));         //  8 MB
    float* cst  = (float*)(ws + (60ull << 20));         //  8 MB
    float* h32  = (float*)(ws + (68ull << 20));         //  8 MB
    float* Whr  = (float*)(ws + (76ull << 20));         // 16 KB
    float* Wxr  = (float*)(ws + (76ull << 20) + 65536);
    float* bfold= (float*)(ws + (76ull << 20) + 131072);

    adj_softmax<<<NN, 256, 0, stream>>>(E1, E2, A2);
    transpose_x<<<(XCOLS * NN) / 256, 256, 0, stream>>>(x, B2x);
    prep_weights<<<1, 256, 0, stream>>>(Wx, bx, Wh, bh, Whr, Wxr, bfold);

    dim3 gg(HCOLS / 128, NN / 128, KSPLIT);   // 8 x 16 x 4 = 512 blocks
    gemm_f16<2><<<gg, 256, 0, stream>>>(A2, B2x, P);     // x path: hi+lo
    reduce_ax<<<(int)(CSZ / 4 / 256), 256, 0, stream>>>(P, AX);

    for (int t = 0; t < TT; ++t) {
        if (t > 0)
            gemm_f16<1><<<gg, 256, 0, stream>>>(A2, hT, P);   // recurrent
        gate_update<<<dim3(NN / 64, BB / 4), 256, 0, stream>>>(AX, P, Whr, Wxr, bfold,
                                                               cst, h32, hT, t, t == 0 ? 1 : 0);
    }

    head_kernel<<<(BB * NN) / 256, 256, 0, stream>>>(h32, Wp, bp, (float*)d_out);
}